// Round 1
// baseline (428.455 us; speedup 1.0000x reference)
//
#include <hip/hip_runtime.h>

// GaussianAgg: z_map construction + S=16 perturbed argmaxes -> mean one-hot.
// Memory-bound: noise [16,131072,33] f32 = 277 MB dominates. Stage noise
// per-(block,sample) tile through LDS for coalescing.

#define NPIX   (8 * 128 * 128)   // 131072
#define KCH    32
#define CCH    33                // K + background
#define SAMP   16
#define TPB    256
#define TILE   (TPB * CCH)       // floats per sample tile = 8448 (33 KB)

__global__ __launch_bounds__(TPB)
void gauss_agg_kernel(const float* __restrict__ zbuf,
                      const float* __restrict__ zfar_p,
                      const float* __restrict__ znear_p,
                      const float* __restrict__ prob,
                      const float* __restrict__ mask,
                      const float* __restrict__ noise,
                      float* __restrict__ out)
{
#pragma clang fp contract(off)
    __shared__ float lds[TILE];
    const int tid = threadIdx.x;
    const int p0  = blockIdx.x * TPB;   // first pixel of this block
    const size_t p = (size_t)p0 + tid;  // this thread's pixel

    const float zfar  = zfar_p[0];
    const float znear = znear_p[0];
    const float denom = zfar - znear;

    // ---- load this pixel's zbuf/prob/mask rows (32 contiguous floats, 128B aligned)
    float zb[KCH], pm[KCH], mk[KCH];
    {
        const float4* zb4 = reinterpret_cast<const float4*>(zbuf + p * KCH);
        const float4* pm4 = reinterpret_cast<const float4*>(prob + p * KCH);
        const float4* mk4 = reinterpret_cast<const float4*>(mask + p * KCH);
        #pragma unroll
        for (int i = 0; i < KCH / 4; ++i) {
            float4 a = zb4[i], b = pm4[i], c = mk4[i];
            zb[4*i+0] = a.x; zb[4*i+1] = a.y; zb[4*i+2] = a.z; zb[4*i+3] = a.w;
            pm[4*i+0] = b.x; pm[4*i+1] = b.y; pm[4*i+2] = b.z; pm[4*i+3] = b.w;
            mk[4*i+0] = c.x; mk[4*i+1] = c.y; mk[4*i+2] = c.z; mk[4*i+3] = c.w;
        }
    }

    // ---- z_inv, z_inv_max (EPS folded into max; max is exact, order-safe)
    float z_inv[KCH];
    float zmax = 1e-10f;
    #pragma unroll
    for (int k = 0; k < KCH; ++k) {
        float zi = ((zfar - zb[k]) / denom) * mk[k];
        z_inv[k] = zi;
        zmax = fmaxf(zmax, zi);
    }

    // ---- z_map[33], rounding order matching ref: ((g*log) + z_inv) - zmax
    float z_map[CCH];
    #pragma unroll
    for (int k = 0; k < KCH; ++k) {
        float lg = logf(1e-12f + pm[k]);
        z_map[k] = ((0.04f * lg) + z_inv[k]) - zmax;
    }
    z_map[KCH] = 1e-10f - zmax;

    // ---- per-sample argmax, accumulate one-hot counts in registers
    int acc[CCH];
    #pragma unroll
    for (int c = 0; c < CCH; ++c) acc[c] = 0;

    for (int s = 0; s < SAMP; ++s) {
        __syncthreads();  // protect LDS tile from previous iteration
        // stage noise[s, p0:p0+256, 0:33] -> LDS (contiguous, 16B aligned)
        {
            const float4* g4 = reinterpret_cast<const float4*>(
                noise + ((size_t)s * NPIX + p0) * CCH);
            float4* l4 = reinterpret_cast<float4*>(lds);
            for (int i = tid; i < TILE / 4; i += TPB) l4[i] = g4[i];
        }
        __syncthreads();

        // first-max argmax (strict >) over z_map + 0.04*noise
        const int base = tid * CCH;
        float best = z_map[0] + (0.04f * lds[base + 0]);
        int bi = 0;
        #pragma unroll
        for (int c = 1; c < CCH; ++c) {
            float v = z_map[c] + (0.04f * lds[base + c]);
            if (v > best) { best = v; bi = c; }
        }
        #pragma unroll
        for (int c = 0; c < CCH; ++c) acc[c] += (bi == c) ? 1 : 0;
    }

    // ---- write counts/16 through LDS for coalesced float4 stores
    __syncthreads();
    {
        const int base = tid * CCH;
        #pragma unroll
        for (int c = 0; c < CCH; ++c)
            lds[base + c] = (float)acc[c] * 0.0625f;  // exact
    }
    __syncthreads();
    {
        const float4* l4 = reinterpret_cast<const float4*>(lds);
        float4* o4 = reinterpret_cast<float4*>(out + (size_t)p0 * CCH);
        for (int i = tid; i < TILE / 4; i += TPB) o4[i] = l4[i];
    }
}

extern "C" void kernel_launch(void* const* d_in, const int* in_sizes, int n_in,
                              void* d_out, int out_size, void* d_ws, size_t ws_size,
                              hipStream_t stream)
{
    const float* zbuf  = (const float*)d_in[0];
    const float* zfar  = (const float*)d_in[1];
    const float* znear = (const float*)d_in[2];
    const float* prob  = (const float*)d_in[3];
    const float* mask  = (const float*)d_in[4];
    const float* noise = (const float*)d_in[5];
    float* out = (float*)d_out;

    dim3 grid(NPIX / TPB), block(TPB);
    gauss_agg_kernel<<<grid, block, 0, stream>>>(zbuf, zfar, znear, prob, mask,
                                                 noise, out);
}